// Round 3
// baseline (258.347 us; speedup 1.0000x reference)
//
#include <hip/hip_runtime.h>
#include <hip/hip_bf16.h>

#define LLEN 512
#define SLEN 64
#define EMBD 16
#define EE 48
#define GG 4
#define NHH 8
#define KDD 4
#define INDIM 224
#define H1D 200
#define H2D 80
#define CHUNK 128
#define PXE 52   // row stride: 48 data + 4 selector floats
#define NT 512   // 8 waves/block; LDS ~36.8KB -> 4 blocks/CU when VGPR<=64

__device__ __forceinline__ float bf2f(unsigned short u) {
    union { unsigned int i; float f; } v; v.i = ((unsigned int)u) << 16; return v.f;
}

template<bool BF16>
__device__ __forceinline__ float ldf(const void* p, int i) {
    if constexpr (BF16) return bf2f(((const unsigned short*)p)[i]);
    else                return ((const float*)p)[i];
}

// raw gather type: load bits now, convert at store time (keeps vmem wait off the path)
template<bool BF16> struct RawSel { using T = float4; };
template<>          struct RawSel<true> { using T = ushort4; };
__device__ __forceinline__ float4 cvt4(ushort4 u) {
    return make_float4(bf2f(u.x), bf2f(u.y), bf2f(u.z), bf2f(u.w));
}
__device__ __forceinline__ float4 cvt4(float4 f) { return f; }

struct Pool {
    float buf[CHUNK * PXE + 16];   // chunk rows (48 data + 4 sel) / attention / MLP scratch
    float part[8][GG][EE];         // [wave][g][e] partial selected-bucket sums
    float hf[12 * EE];             // H transposed fp32: hf[j*48+e] = H[e][j]
    float feat[INDIM];
    float q[NHH * KDD];
    float red[128];
    int   pcw[8][2];               // per-wave counts: wave w -> groups (w>>2)*2 + {0,1}
    int   len;
    float mu, rstd;
};

template<bool BF16>
__device__ void sdim_body(Pool& P,
    const int* uid, const int* ut1, const int* ut2, const int* ut3, const int* ut4,
    const int* lb_g, const int* lb_s, const int* lb_c,
    const int* lt_g, const int* lt_s, const int* lt_c,
    const int* st_g, const int* st_s, const int* st_c,
    const void* tbl, const void* Hm,
    const void* wq, const void* bq, const void* wk, const void* bk,
    const void* wvv, const void* bv, const void* wo, const void* bo,
    const void* w1, const void* b1, const void* g1, const void* be1,
    const void* w2, const void* b2, const void* g2, const void* be2,
    const void* w3, const void* b3, void* outp)
{
    using RawT = typename RawSel<BF16>::T;
    const int b = blockIdx.x;
    const int tid = threadIdx.x;
    const int lane = tid & 63;
    const int wid = __builtin_amdgcn_readfirstlane(tid >> 6);   // 0..7 uniform

    // ---- phase-1 gather-job constants: loop-invariant, computed ONCE ----
    const int* jsrc[3]; int jq4[3], jlds[3];
    #pragma unroll
    for (int i = 0; i < 3; i++) {
        int f = tid + NT * i;
        int p = f / 12, qq = f - 12 * p, fe = qq >> 2;
        const int* idp = (fe == 0) ? lt_g : (fe == 1) ? lt_s : lt_c;
        jsrc[i] = idp + b * LLEN + p;
        jq4[i]  = (qq & 3) << 2;
        jlds[i] = p * PXE + (qq << 2);
    }
    const int pB = ((wid & 3) << 5) | (lane & 31);   // position within chunk (phase B/C)
    const int gB = ((wid >> 2) << 1) | (lane >> 5);  // LSH group handled by this thread
    const int* vsrc = lt_g + b * LLEN + pB;

    // ---- issue chunk-0 id loads immediately (nothing depends on them yet) ----
    int ids[3];
    #pragma unroll
    for (int i = 0; i < 3; i++) ids[i] = jsrc[i][0];

    // ---------------- phase 0: H -> fp32 transposed LDS; Xu/Xi embeds ----------------
    for (int i = tid; i < 12 * EE; i += NT) {
        int j = i / EE, e = i - j * EE;
        P.hf[i] = ldf<BF16>(Hm, e * 12 + j);
    }
    if (tid < 80) {
        int f = tid >> 4, e = tid & 15;
        int id = (f == 0) ? uid[b] : (f == 1) ? ut1[b] : (f == 2) ? ut2[b] : (f == 3) ? ut3[b] : ut4[b];
        P.feat[tid] = ldf<BF16>(tbl, id * EMBD + e);
    } else if (tid < 128) {
        int t = tid - 80; int f = t >> 4, e = t & 15;
        int id = (f == 0) ? lb_g[b] : (f == 1) ? lb_s[b] : lb_c[b];
        P.feat[80 + t] = ldf<BF16>(tbl, id * EMBD + e);
    }
    __syncthreads();

    // ---------------- phase 0.5: q projection + item LSH dots (FP order unchanged) ---
    if (tid < 32) {
        float acc = ldf<BF16>(bq, tid);
        for (int e = 0; e < EE; e++) acc += P.feat[80 + e] * ldf<BF16>(wq, e * 32 + tid);
        P.q[tid] = acc;
    }
    if (tid >= 64 && tid < 76) {
        int j = tid - 64;
        float acc = 0.f;
        for (int e = 0; e < EE; e++) acc += P.feat[80 + e] * P.hf[j * EE + e];
        P.red[j] = acc;
    }
    // ---- gather chunk 0 (waits ids), store to buf (buf unused by phase 0/0.5) ----
    {
        RawT rv0 = ((const RawT*)tbl)[(ids[0] * EMBD + jq4[0]) >> 2];
        RawT rv1 = ((const RawT*)tbl)[(ids[1] * EMBD + jq4[1]) >> 2];
        RawT rv2 = ((const RawT*)tbl)[(ids[2] * EMBD + jq4[2]) >> 2];
        *(float4*)&P.buf[jlds[0]] = cvt4(rv0);
        *(float4*)&P.buf[jlds[1]] = cvt4(rv1);
        *(float4*)&P.buf[jlds[2]] = cvt4(rv2);
    }
    #pragma unroll
    for (int i = 0; i < 3; i++) ids[i] = jsrc[i][CHUNK];   // ids for chunk 1
    int vld = vsrc[0];                                     // valid flag for chunk 0
    __syncthreads();   // red + chunk-0 rows visible

    // per-thread item code for this thread's group (replaces icode[] + barrier)
    int icb = 0;
    #pragma unroll
    for (int m = 0; m < 3; m++) if (P.red[gB * 3 + m] > 0.f) icb |= (1 << m);

    // ---------------- phase 1: 4 chunks, register-double-buffered gathers ----------
    // FULLY UNROLLED (constant trip count): all ch-dependent branches constant-fold,
    // all prefetch temporaries are statically-indexed short-lived SSA values -> no
    // scratch spill (round-2 regression: 160B/thread spilled from the rolled loop).
    float accg[GG] = {0.f, 0.f, 0.f, 0.f};
    int cnt0 = 0, cnt1 = 0;
    const int offs = (lane < 52) ? lane : 51;
    const bool has1 = (tid < (SLEN * 12 - NT));   // tid < 256 (2nd short-term job)

    #pragma unroll
    for (int ch = 0; ch < 4; ++ch) {
        // ---- issue next-chunk gathers (ch<3) or short-term id loads (ch==3) ----
        RawT rvn0, rvn1, rvn2;
        int aid0 = 0, aid1 = 0, aq0 = 0, aq1 = 0, al0 = 0, al1 = 0;
        if (ch < 3) {
            rvn0 = ((const RawT*)tbl)[(ids[0] * EMBD + jq4[0]) >> 2];
            rvn1 = ((const RawT*)tbl)[(ids[1] * EMBD + jq4[1]) >> 2];
            rvn2 = ((const RawT*)tbl)[(ids[2] * EMBD + jq4[2]) >> 2];
        } else {
            int f0 = tid; int p0 = f0 / 12, q0 = f0 - 12 * p0, fe0 = q0 >> 2;
            const int* idp0 = (fe0 == 0) ? st_g : (fe0 == 1) ? st_s : st_c;
            aid0 = idp0[b * SLEN + p0]; aq0 = (q0 & 3) << 2; al0 = p0 * PXE + (q0 << 2);
            if (has1) {
                int f1 = tid + NT; int p1 = f1 / 12, q1 = f1 - 12 * p1, fe1 = q1 >> 2;
                const int* idp1 = (fe1 == 0) ? st_g : (fe1 == 1) ? st_s : st_c;
                aid1 = idp1[b * SLEN + p1]; aq1 = (q1 & 3) << 2; al1 = p1 * PXE + (q1 << 2);
            }
        }
        // ---- B: LSH codes + selector for (pB, gB); EXACT FP order (sign-safe) ----
        {
            const float* row = &P.buf[pB * PXE];
            float4 x[12];
            #pragma unroll
            for (int k = 0; k < 12; k++) x[k] = *(const float4*)(row + 4 * k);
            float acc[3];
            #pragma unroll
            for (int jj = 0; jj < 3; jj++) {
                const float4* hr = (const float4*)&P.hf[(3 * gB + jj) * EE];
                float s = 0.f;
                #pragma unroll
                for (int k = 0; k < 12; k++) {
                    float4 h4 = hr[k];
                    s += x[k].x * h4.x + x[k].y * h4.y + x[k].z * h4.z + x[k].w * h4.w;
                }
                acc[jj] = s;
            }
            int code = 0;
            #pragma unroll
            for (int m = 0; m < 3; m++) if (acc[m] > 0.f) code |= (1 << m);
            int valid = (vld != 0);
            P.buf[pB * PXE + 48 + gB] = (code == icb && valid) ? 1.f : 0.f;
            unsigned long long m = __ballot(code == icb);
            cnt0 += __popcll(m & 0xFFFFFFFFull);
            cnt1 += __popcll(m >> 32);
        }
        __syncthreads();
        // ---- C: selected-bucket accumulation (16 positions/wave, readlane bcast) ----
        {
            const float* basep = &P.buf[(wid << 4) * PXE] + offs;
            #pragma unroll
            for (int i = 0; i < 16; i++) {
                float xv = basep[i * PXE];
                #pragma unroll
                for (int g = 0; g < GG; g++) {
                    float sel = __int_as_float(
                        __builtin_amdgcn_readlane(__float_as_int(xv), 48 + g));
                    accg[g] += sel * xv;
                }
            }
        }
        RawT arv0, arv1;
        if (ch == 3) {   // issue short-term gathers (waits aids) before the barrier
            arv0 = ((const RawT*)tbl)[(aid0 * EMBD + aq0) >> 2];
            if (has1) arv1 = ((const RawT*)tbl)[(aid1 * EMBD + aq1) >> 2];
        }
        __syncthreads();
        if (ch < 3) {
            *(float4*)&P.buf[jlds[0]] = cvt4(rvn0);
            *(float4*)&P.buf[jlds[1]] = cvt4(rvn1);
            *(float4*)&P.buf[jlds[2]] = cvt4(rvn2);
            if (ch < 2) {
                #pragma unroll
                for (int i = 0; i < 3; i++) ids[i] = jsrc[i][(ch + 2) * CHUNK];
            }
            vld = vsrc[(ch + 1) * CHUNK];
            __syncthreads();
        } else {
            *(float4*)&P.buf[al0] = cvt4(arv0);
            if (has1) *(float4*)&P.buf[al1] = cvt4(arv1);
        }
    }

    // ---------------- flush partials + attention prep (before one barrier) ----------
    float* Xs   = P.buf;                 // [64][PXE]
    float* wkqT = P.buf + SLEN * PXE;    // [8][52] transposed, stride 52 (bank-spread)
    float* bkq  = wkqT + NHH * PXE;      // [8]
    float* sc   = bkq + NHH;             // [64][8]  scores/attn transposed
    float* su   = sc + SLEN * NHH;       // [8][48]
    float* sctx = su + NHH * EE;         // [32]

    if (lane < EE) {
        #pragma unroll
        for (int g = 0; g < GG; g++) P.part[wid][g][lane] = accg[g];
    }
    if (lane == 0) { P.pcw[wid][0] = cnt0; P.pcw[wid][1] = cnt1; }
    for (int t = tid; t < EE * NHH; t += NT) {
        int e = t >> 3, h = t & 7;
        float acc = 0.f;
        #pragma unroll
        for (int d = 0; d < KDD; d++) acc += ldf<BF16>(wk, e * 32 + h * 4 + d) * P.q[h * 4 + d];
        wkqT[h * PXE + e] = acc;
    }
    if (tid < NHH) {
        float acc = 0.f;
        #pragma unroll
        for (int d = 0; d < KDD; d++) acc += ldf<BF16>(bk, tid * 4 + d) * P.q[tid * 4 + d];
        bkq[tid] = acc;
    }
    if (tid < 64) {
        unsigned long long msk = __ballot(st_g[b * SLEN + tid] != 0);
        if (tid == 0) P.len = __popcll(msk);
    }
    __syncthreads();

    // ---------------- phase 2: long-term interest -> feat[128:176] ----------------
    if (tid < EE) {
        float r = 0.f;
        #pragma unroll
        for (int g = 0; g < GG; g++) {
            int wb = (g >> 1) << 2;
            int h = g & 1;
            float c = (float)(P.pcw[wb][h] + P.pcw[wb + 1][h] + P.pcw[wb + 2][h] + P.pcw[wb + 3][h]);
            float s = 0.f;
            #pragma unroll
            for (int w = 0; w < 8; w++) s += P.part[w][g][tid];
            r += s / fmaxf(c, 1.0f);
        }
        P.feat[128 + tid] = r * 0.25f;
    }

    // ---- scores: float4 dot, (s=tid>>3, h=tid&7); broadcast Xs, stride-52 wkqT ----
    {
        int s = tid >> 3, h = tid & 7;
        const float* xr = &Xs[s * PXE];
        const float* wr = &wkqT[h * PXE];
        float acc = bkq[h];
        #pragma unroll
        for (int k = 0; k < 12; k++) {
            float4 xv = *(const float4*)(xr + 4 * k);
            float4 wv = *(const float4*)(wr + 4 * k);
            acc += xv.x * wv.x + xv.y * wv.y + xv.z * wv.z + xv.w * wv.w;
        }
        acc *= 0.5f;
        if (s >= P.len) acc -= 1e9f;
        sc[s * NHH + h] = acc;
    }
    __syncthreads();
    // softmax: wave wid handles head wid, lane = s
    {
        float v = sc[lane * NHH + wid];
        float mx = v;
        #pragma unroll
        for (int o = 32; o; o >>= 1) mx = fmaxf(mx, __shfl_xor(mx, o));
        float ex = __expf(v - mx);
        float sm = ex;
        #pragma unroll
        for (int o = 32; o; o >>= 1) sm += __shfl_xor(sm, o);
        sc[lane * NHH + wid] = ex / sm;
    }
    __syncthreads();
    if (tid < NHH * EE) {
        int h = tid / EE, e = tid - h * EE;
        float acc = 0.f;
        #pragma unroll 4
        for (int s = 0; s < SLEN; s++) acc += sc[s * NHH + h] * Xs[s * PXE + e];
        su[tid] = acc;
    }
    __syncthreads();
    if (tid < 32) {
        float acc = ldf<BF16>(bv, tid);
        int h = tid >> 2;
        for (int e = 0; e < EE; e++) acc += su[h * EE + e] * ldf<BF16>(wvv, e * 32 + tid);
        sctx[tid] = acc;
    }
    __syncthreads();
    if (tid < EE) {
        float acc = ldf<BF16>(bo, tid);
        #pragma unroll
        for (int i = 0; i < 32; i++) acc += sctx[i] * ldf<BF16>(wo, i * EE + tid);
        P.feat[176 + tid] = acc;
    }
    __syncthreads();

    // ---------------- phase 4: MLP (4-way split chains, float4 feat reads) ----------
    float z1p = 0.f;
    if (tid < H1D) {
        float a0 = ldf<BF16>(b1, tid), a1 = 0.f, a2 = 0.f, a3 = 0.f;
        #pragma unroll 2
        for (int i = 0; i < 112; i += 4) {
            float4 f4 = *(const float4*)&P.feat[i];
            a0 += f4.x * ldf<BF16>(w1, (i + 0) * H1D + tid);
            a1 += f4.y * ldf<BF16>(w1, (i + 1) * H1D + tid);
            a2 += f4.z * ldf<BF16>(w1, (i + 2) * H1D + tid);
            a3 += f4.w * ldf<BF16>(w1, (i + 3) * H1D + tid);
        }
        z1p = (a0 + a1) + (a2 + a3);
    } else if (tid >= 256 && tid < 256 + H1D) {
        int o = tid - 256;
        float a0 = 0.f, a1 = 0.f, a2 = 0.f, a3 = 0.f;
        #pragma unroll 2
        for (int i = 112; i < INDIM; i += 4) {
            float4 f4 = *(const float4*)&P.feat[i];
            a0 += f4.x * ldf<BF16>(w1, (i + 0) * H1D + o);
            a1 += f4.y * ldf<BF16>(w1, (i + 1) * H1D + o);
            a2 += f4.z * ldf<BF16>(w1, (i + 2) * H1D + o);
            a3 += f4.w * ldf<BF16>(w1, (i + 3) * H1D + o);
        }
        P.buf[640 + o] = (a0 + a1) + (a2 + a3);
    }
    __syncthreads();
    float z1 = 0.f;
    if (tid < H1D) { z1 = z1p + P.buf[640 + tid]; P.buf[tid] = z1; }
    __syncthreads();
    if (tid < 64) {
        float sm = 0.f, sq = 0.f;
        for (int j = tid; j < H1D; j += 64) { float v = P.buf[j]; sm += v; sq += v * v; }
        #pragma unroll
        for (int o = 32; o; o >>= 1) { sm += __shfl_xor(sm, o); sq += __shfl_xor(sq, o); }
        if (tid == 0) { float mu = sm / H1D; P.mu = mu; P.rstd = rsqrtf(sq / H1D - mu * mu + 1e-3f); }
    }
    __syncthreads();
    if (tid < H1D) {
        float h = fmaxf(ldf<BF16>(g1, tid) * (z1 - P.mu) * P.rstd + ldf<BF16>(be1, tid), 0.f);
        P.buf[256 + tid] = h;
    }
    __syncthreads();
    float z2p = 0.f;
    if (tid < H2D) {
        float a0 = ldf<BF16>(b2, tid), a1 = 0.f, a2 = 0.f, a3 = 0.f;
        #pragma unroll 2
        for (int i = 0; i < 100; i += 4) {
            float4 f4 = *(const float4*)&P.buf[256 + i];
            a0 += f4.x * ldf<BF16>(w2, (i + 0) * H2D + tid);
            a1 += f4.y * ldf<BF16>(w2, (i + 1) * H2D + tid);
            a2 += f4.z * ldf<BF16>(w2, (i + 2) * H2D + tid);
            a3 += f4.w * ldf<BF16>(w2, (i + 3) * H2D + tid);
        }
        z2p = (a0 + a1) + (a2 + a3);
    } else if (tid >= 256 && tid < 256 + H2D) {
        int o = tid - 256;
        float a0 = 0.f, a1 = 0.f, a2 = 0.f, a3 = 0.f;
        #pragma unroll 2
        for (int i = 100; i < H1D; i += 4) {
            float4 f4 = *(const float4*)&P.buf[256 + i];
            a0 += f4.x * ldf<BF16>(w2, (i + 0) * H2D + o);
            a1 += f4.y * ldf<BF16>(w2, (i + 1) * H2D + o);
            a2 += f4.z * ldf<BF16>(w2, (i + 2) * H2D + o);
            a3 += f4.w * ldf<BF16>(w2, (i + 3) * H2D + o);
        }
        P.buf[640 + o] = (a0 + a1) + (a2 + a3);
    }
    __syncthreads();
    float z2 = 0.f;
    if (tid < H2D) { z2 = z2p + P.buf[640 + tid]; P.buf[tid] = z2; }
    __syncthreads();
    if (tid < 64) {
        float sm = 0.f, sq = 0.f;
        for (int j = tid; j < H2D; j += 64) { float v = P.buf[j]; sm += v; sq += v * v; }
        #pragma unroll
        for (int o = 32; o; o >>= 1) { sm += __shfl_xor(sm, o); sq += __shfl_xor(sq, o); }
        if (tid == 0) { float mu = sm / H2D; P.mu = mu; P.rstd = rsqrtf(sq / H2D - mu * mu + 1e-3f); }
    }
    __syncthreads();
    if (tid < H2D) {
        float h = fmaxf(ldf<BF16>(g2, tid) * (z2 - P.mu) * P.rstd + ldf<BF16>(be2, tid), 0.f);
        P.red[tid] = h * ldf<BF16>(w3, tid);
    }
    __syncthreads();
    if (tid < 64) {
        float v = P.red[tid] + ((tid < H2D - 64) ? P.red[64 + tid] : 0.f);
        #pragma unroll
        for (int o = 32; o; o >>= 1) v += __shfl_xor(v, o);
        if (tid == 0) {
            float acc = ldf<BF16>(b3, 0) + v;
            float sig = 1.f / (1.f + __expf(-acc));
            if constexpr (BF16) ((__hip_bfloat16*)outp)[b] = __float2bfloat16(sig);
            else                ((float*)outp)[b] = sig;
        }
    }
}

__global__ __launch_bounds__(NT, 6) void sdim_fwd(
    const int* __restrict__ uid, const int* __restrict__ ut1, const int* __restrict__ ut2,
    const int* __restrict__ ut3, const int* __restrict__ ut4,
    const int* __restrict__ lb_g, const int* __restrict__ lb_s, const int* __restrict__ lb_c,
    const int* __restrict__ lt_g, const int* __restrict__ lt_s, const int* __restrict__ lt_c,
    const int* __restrict__ st_g, const int* __restrict__ st_s, const int* __restrict__ st_c,
    const void* __restrict__ tbl, const void* __restrict__ Hm,
    const void* __restrict__ wq, const void* __restrict__ bq,
    const void* __restrict__ wk, const void* __restrict__ bk,
    const void* __restrict__ wvv, const void* __restrict__ bv,
    const void* __restrict__ wo, const void* __restrict__ bo,
    const void* __restrict__ w1, const void* __restrict__ b1,
    const void* __restrict__ g1, const void* __restrict__ be1,
    const void* __restrict__ w2, const void* __restrict__ b2,
    const void* __restrict__ g2, const void* __restrict__ be2,
    const void* __restrict__ w3, const void* __restrict__ b3,
    void* __restrict__ outp)
{
    __shared__ Pool P;
    __shared__ int s_isbf;
    // in-block dtype detection: even ushort indices of bf16 data are small values
    // (exp<127); of fp32 they are random mantissa bits (P[all 128 exp<127] ~ 2^-128)
    if (threadIdx.x < 64) {
        int big = 0;
        for (int i = (threadIdx.x & 63); i < 128; i += 64) {
            unsigned short u = ((const unsigned short*)tbl)[2 * i];
            if (((u >> 7) & 0xFF) >= 127) big = 1;
        }
        unsigned long long m = __ballot(big);
        if (threadIdx.x == 0) s_isbf = (m == 0ull) ? 1 : 0;
    }
    __syncthreads();
    if (s_isbf)
        sdim_body<true >(P, uid, ut1, ut2, ut3, ut4, lb_g, lb_s, lb_c, lt_g, lt_s, lt_c,
                         st_g, st_s, st_c, tbl, Hm, wq, bq, wk, bk, wvv, bv, wo, bo,
                         w1, b1, g1, be1, w2, b2, g2, be2, w3, b3, outp);
    else
        sdim_body<false>(P, uid, ut1, ut2, ut3, ut4, lb_g, lb_s, lb_c, lt_g, lt_s, lt_c,
                         st_g, st_s, st_c, tbl, Hm, wq, bq, wk, bk, wvv, bv, wo, bo,
                         w1, b1, g1, be1, w2, b2, g2, be2, w3, b3, outp);
}

extern "C" void kernel_launch(void* const* d_in, const int* in_sizes, int n_in,
                              void* d_out, int out_size, void* d_ws, size_t ws_size,
                              hipStream_t stream) {
    const int B = in_sizes[0];   // batch = 1024
    sdim_fwd<<<B, NT, 0, stream>>>(
        (const int*)d_in[0],  (const int*)d_in[1],  (const int*)d_in[2],
        (const int*)d_in[3],  (const int*)d_in[4],
        (const int*)d_in[5],  (const int*)d_in[6],  (const int*)d_in[7],
        (const int*)d_in[8],  (const int*)d_in[9],  (const int*)d_in[10],
        (const int*)d_in[11], (const int*)d_in[12], (const int*)d_in[13],
        (const void*)d_in[14], (const void*)d_in[15],
        (const void*)d_in[16], (const void*)d_in[17],
        (const void*)d_in[18], (const void*)d_in[19],
        (const void*)d_in[20], (const void*)d_in[21],
        (const void*)d_in[22], (const void*)d_in[23],
        (const void*)d_in[24], (const void*)d_in[25],
        (const void*)d_in[26], (const void*)d_in[27],
        (const void*)d_in[28], (const void*)d_in[29],
        (const void*)d_in[30], (const void*)d_in[31],
        (const void*)d_in[32], (const void*)d_in[33],
        d_out);
}

// Round 4
// 210.080 us; speedup vs baseline: 1.2298x; 1.2298x over previous
//
#include <hip/hip_runtime.h>
#include <hip/hip_bf16.h>

#define LLEN 512
#define SLEN 64
#define EMBD 16
#define EE 48
#define GG 4
#define NHH 8
#define KDD 4
#define INDIM 224
#define H1D 200
#define H2D 80
#define CHUNK 128
#define PXE 52   // row stride: 48 data + 4 selector floats
#define NT 512   // 8 waves/block; LDS ~36.8KB -> 4 blocks/CU when VGPR<=64

__device__ __forceinline__ float bf2f(unsigned short u) {
    union { unsigned int i; float f; } v; v.i = ((unsigned int)u) << 16; return v.f;
}

template<bool BF16>
__device__ __forceinline__ float ldf(const void* p, int i) {
    if constexpr (BF16) return bf2f(((const unsigned short*)p)[i]);
    else                return ((const float*)p)[i];
}

template<bool BF16>
__device__ __forceinline__ float4 ld4(const void* p, int i4) {
    if constexpr (BF16) {
        ushort4 u = ((const ushort4*)p)[i4 >> 2];
        return make_float4(bf2f(u.x), bf2f(u.y), bf2f(u.z), bf2f(u.w));
    } else {
        return ((const float4*)p)[i4 >> 2];
    }
}

struct Pool {
    float buf[CHUNK * PXE + 16];   // chunk rows (48 data + 4 sel) / attention / MLP scratch
    float part[8][GG][EE];         // [wave][g][e] partial selected-bucket sums
    float hf[12 * EE];             // H transposed fp32: hf[j*48+e] = H[e][j]
    float feat[INDIM];
    float q[NHH * KDD];
    float red[128];
    int   pcw[8][2];               // per-wave counts: wave w -> groups (w>>2)*2 + {0,1}
    int   len;
    float mu, rstd;
};

template<bool BF16>
__device__ void sdim_body(Pool& P,
    const int* uid, const int* ut1, const int* ut2, const int* ut3, const int* ut4,
    const int* lb_g, const int* lb_s, const int* lb_c,
    const int* lt_g, const int* lt_s, const int* lt_c,
    const int* st_g, const int* st_s, const int* st_c,
    const void* tbl, const void* Hm,
    const void* wq, const void* bq, const void* wk, const void* bk,
    const void* wvv, const void* bv, const void* wo, const void* bo,
    const void* w1, const void* b1, const void* g1, const void* be1,
    const void* w2, const void* b2, const void* g2, const void* be2,
    const void* w3, const void* b3, void* outp)
{
    const int b = blockIdx.x;
    const int tid = threadIdx.x;
    const int lane = tid & 63;
    const int wid = __builtin_amdgcn_readfirstlane(tid >> 6);   // 0..7 uniform

    const int pB = ((wid & 3) << 5) | (lane & 31);   // position within chunk (phase B/C)
    const int gB = ((wid >> 2) << 1) | (lane >> 5);  // LSH group handled by this thread

    // ---- chunk-0 id/valid prefetch (4 ints/thread; only these cross barriers) ----
    int pid0, pid1, pid2, vld;
    {
        int f0 = tid, f1 = tid + NT, f2 = tid + 2 * NT;
        int p0 = f0 / 12, q0 = f0 - 12 * p0, e0 = q0 >> 2;
        int p1 = f1 / 12, q1 = f1 - 12 * p1, e1 = q1 >> 2;
        int p2 = f2 / 12, q2 = f2 - 12 * p2, e2 = q2 >> 2;
        const int* s0 = (e0 == 0) ? lt_g : (e0 == 1) ? lt_s : lt_c;
        const int* s1 = (e1 == 0) ? lt_g : (e1 == 1) ? lt_s : lt_c;
        const int* s2 = (e2 == 0) ? lt_g : (e2 == 1) ? lt_s : lt_c;
        pid0 = s0[b * LLEN + p0];
        pid1 = s1[b * LLEN + p1];
        pid2 = s2[b * LLEN + p2];
        vld  = lt_g[b * LLEN + pB];
    }

    // ---------------- phase 0: H -> fp32 transposed LDS; Xu/Xi embeds ----------------
    for (int i = tid; i < 12 * EE; i += NT) {
        int j = i / EE, e = i - j * EE;
        P.hf[i] = ldf<BF16>(Hm, e * 12 + j);
    }
    if (tid < 80) {
        int f = tid >> 4, e = tid & 15;
        int id = (f == 0) ? uid[b] : (f == 1) ? ut1[b] : (f == 2) ? ut2[b] : (f == 3) ? ut3[b] : ut4[b];
        P.feat[tid] = ldf<BF16>(tbl, id * EMBD + e);
    } else if (tid < 128) {
        int t = tid - 80; int f = t >> 4, e = t & 15;
        int id = (f == 0) ? lb_g[b] : (f == 1) ? lb_s[b] : lb_c[b];
        P.feat[80 + t] = ldf<BF16>(tbl, id * EMBD + e);
    }
    __syncthreads();

    // ---------------- phase 0.5: q projection + item LSH dots (FP order unchanged) ---
    if (tid < 32) {
        float acc = ldf<BF16>(bq, tid);
        for (int e = 0; e < EE; e++) acc += P.feat[80 + e] * ldf<BF16>(wq, e * 32 + tid);
        P.q[tid] = acc;
    }
    if (tid >= 64 && tid < 76) {
        int j = tid - 64;
        float acc = 0.f;
        for (int e = 0; e < EE; e++) acc += P.feat[80 + e] * P.hf[j * EE + e];
        P.red[j] = acc;
    }
    __syncthreads();

    // per-thread item code for this thread's group
    int icb = 0;
    #pragma unroll
    for (int m = 0; m < 3; m++) if (P.red[gB * 3 + m] > 0.f) icb |= (1 << m);

    // ---------------- phase 1: 4 chunks; gathers in-place (round-1 proven structure);
    // only next-chunk ids+valid (4 ints) are prefetched across the iteration. --------
    float accg[GG] = {0.f, 0.f, 0.f, 0.f};
    int cnt0 = 0, cnt1 = 0;
    const int offs = (lane < 52) ? lane : 51;

    for (int ch = 0; ch < 4; ++ch) {
        // ---- A: gather (ids already in regs) -> LDS stores; recompute addressing ----
        {
            float4 v0, v1, v2;
            {
                int f0 = tid, f1 = tid + NT, f2 = tid + 2 * NT;
                int q0 = f0 - 12 * (f0 / 12);
                int q1 = f1 - 12 * (f1 / 12);
                int q2 = f2 - 12 * (f2 / 12);
                v0 = ld4<BF16>(tbl, pid0 * EMBD + ((q0 & 3) << 2));
                v1 = ld4<BF16>(tbl, pid1 * EMBD + ((q1 & 3) << 2));
                v2 = ld4<BF16>(tbl, pid2 * EMBD + ((q2 & 3) << 2));
            }
            {
                int f0 = tid, f1 = tid + NT, f2 = tid + 2 * NT;
                int p0 = f0 / 12, q0 = f0 - 12 * p0;
                int p1 = f1 / 12, q1 = f1 - 12 * p1;
                int p2 = f2 / 12, q2 = f2 - 12 * p2;
                *(float4*)&P.buf[p0 * PXE + (q0 << 2)] = v0;
                *(float4*)&P.buf[p1 * PXE + (q1 << 2)] = v1;
                *(float4*)&P.buf[p2 * PXE + (q2 << 2)] = v2;
            }
        }
        // ---- prefetch next-chunk ids + valid (clamped in-bounds for ch==3) ----
        {
            const int nbase = ((ch < 3) ? (ch + 1) : 3) * CHUNK;
            int f0 = tid, f1 = tid + NT, f2 = tid + 2 * NT;
            int p0 = f0 / 12, e0 = (f0 - 12 * p0) >> 2;
            int p1 = f1 / 12, e1 = (f1 - 12 * p1) >> 2;
            int p2 = f2 / 12, e2 = (f2 - 12 * p2) >> 2;
            const int* s0 = (e0 == 0) ? lt_g : (e0 == 1) ? lt_s : lt_c;
            const int* s1 = (e1 == 0) ? lt_g : (e1 == 1) ? lt_s : lt_c;
            const int* s2 = (e2 == 0) ? lt_g : (e2 == 1) ? lt_s : lt_c;
            pid0 = s0[b * LLEN + nbase + p0];
            pid1 = s1[b * LLEN + nbase + p1];
            pid2 = s2[b * LLEN + nbase + p2];
            // vld for next chunk loaded AFTER B consumes current vld (see below)
            // (kept here as a separate named value to avoid WAR on vld)
        }
        __syncthreads();
        // ---- B: LSH codes + selector for (pB, gB); EXACT FP order (sign-safe) ----
        int nvld;
        {
            const int nbase = ((ch < 3) ? (ch + 1) : 3) * CHUNK;
            nvld = lt_g[b * LLEN + nbase + pB];   // prefetch next valid flag
            const float* row = &P.buf[pB * PXE];
            float4 x[12];
            #pragma unroll
            for (int k = 0; k < 12; k++) x[k] = *(const float4*)(row + 4 * k);
            float acc[3];
            #pragma unroll
            for (int jj = 0; jj < 3; jj++) {
                const float4* hr = (const float4*)&P.hf[(3 * gB + jj) * EE];
                float s = 0.f;
                #pragma unroll
                for (int k = 0; k < 12; k++) {
                    float4 h4 = hr[k];
                    s += x[k].x * h4.x + x[k].y * h4.y + x[k].z * h4.z + x[k].w * h4.w;
                }
                acc[jj] = s;
            }
            int code = 0;
            #pragma unroll
            for (int m = 0; m < 3; m++) if (acc[m] > 0.f) code |= (1 << m);
            int valid = (vld != 0);
            P.buf[pB * PXE + 48 + gB] = (code == icb && valid) ? 1.f : 0.f;
            unsigned long long m = __ballot(code == icb);
            cnt0 += __popcll(m & 0xFFFFFFFFull);
            cnt1 += __popcll(m >> 32);
        }
        vld = nvld;
        __syncthreads();
        // ---- C: selected-bucket accumulation (16 positions/wave, readlane bcast) ----
        {
            const float* basep = &P.buf[(wid << 4) * PXE] + offs;
            #pragma unroll
            for (int i = 0; i < 16; i++) {
                float xv = basep[i * PXE];
                #pragma unroll
                for (int g = 0; g < GG; g++) {
                    float sel = __int_as_float(
                        __builtin_amdgcn_readlane(__float_as_int(xv), 48 + g));
                    accg[g] += sel * xv;
                }
            }
        }
        __syncthreads();
    }

    // ---------------- flush partials + short-term gather + attention prep ----------
    float* Xs   = P.buf;                 // [64][PXE]
    float* wkqT = P.buf + SLEN * PXE;    // [8][52] transposed, stride 52 (bank-spread)
    float* bkq  = wkqT + NHH * PXE;      // [8]
    float* sc   = bkq + NHH;             // [64][8]  scores/attn transposed
    float* su   = sc + SLEN * NHH;       // [8][48]
    float* sctx = su + NHH * EE;         // [32]

    if (lane < EE) {
        #pragma unroll
        for (int g = 0; g < GG; g++) P.part[wid][g][lane] = accg[g];
    }
    if (lane == 0) { P.pcw[wid][0] = cnt0; P.pcw[wid][1] = cnt1; }
    {
        // 768 short-term gather jobs: 1 for all threads + a 2nd for tid<256
        int f0 = tid;
        int p0 = f0 / 12, q0 = f0 - 12 * p0, fe0 = q0 >> 2;
        const int* idp0 = (fe0 == 0) ? st_g : (fe0 == 1) ? st_s : st_c;
        int id0 = idp0[b * SLEN + p0];
        const bool has1 = (tid < (SLEN * 12 - NT));   // tid < 256
        int id1 = 0, p1 = 0, q1 = 0;
        if (has1) {
            int f1 = tid + NT;
            p1 = f1 / 12; q1 = f1 - 12 * p1; int fe1 = q1 >> 2;
            const int* idp1 = (fe1 == 0) ? st_g : (fe1 == 1) ? st_s : st_c;
            id1 = idp1[b * SLEN + p1];
        }
        float4 v0 = ld4<BF16>(tbl, id0 * EMBD + ((q0 & 3) << 2));
        *(float4*)&Xs[p0 * PXE + (q0 << 2)] = v0;
        if (has1) {
            float4 v1 = ld4<BF16>(tbl, id1 * EMBD + ((q1 & 3) << 2));
            *(float4*)&Xs[p1 * PXE + (q1 << 2)] = v1;
        }
    }
    for (int t = tid; t < EE * NHH; t += NT) {
        int e = t >> 3, h = t & 7;
        float acc = 0.f;
        #pragma unroll
        for (int d = 0; d < KDD; d++) acc += ldf<BF16>(wk, e * 32 + h * 4 + d) * P.q[h * 4 + d];
        wkqT[h * PXE + e] = acc;
    }
    if (tid < NHH) {
        float acc = 0.f;
        #pragma unroll
        for (int d = 0; d < KDD; d++) acc += ldf<BF16>(bk, tid * 4 + d) * P.q[tid * 4 + d];
        bkq[tid] = acc;
    }
    if (tid < 64) {
        unsigned long long msk = __ballot(st_g[b * SLEN + tid] != 0);
        if (tid == 0) P.len = __popcll(msk);
    }
    __syncthreads();

    // ---------------- phase 2: long-term interest -> feat[128:176] ----------------
    if (tid < EE) {
        float r = 0.f;
        #pragma unroll
        for (int g = 0; g < GG; g++) {
            int wb = (g >> 1) << 2;
            int h = g & 1;
            float c = (float)(P.pcw[wb][h] + P.pcw[wb + 1][h] + P.pcw[wb + 2][h] + P.pcw[wb + 3][h]);
            float s = 0.f;
            #pragma unroll
            for (int w = 0; w < 8; w++) s += P.part[w][g][tid];
            r += s / fmaxf(c, 1.0f);
        }
        P.feat[128 + tid] = r * 0.25f;
    }

    // ---- scores: float4 dot, (s=tid>>3, h=tid&7); broadcast Xs, stride-52 wkqT ----
    {
        int s = tid >> 3, h = tid & 7;
        const float* xr = &Xs[s * PXE];
        const float* wr = &wkqT[h * PXE];
        float acc = bkq[h];
        #pragma unroll
        for (int k = 0; k < 12; k++) {
            float4 xv = *(const float4*)(xr + 4 * k);
            float4 wv = *(const float4*)(wr + 4 * k);
            acc += xv.x * wv.x + xv.y * wv.y + xv.z * wv.z + xv.w * wv.w;
        }
        acc *= 0.5f;
        if (s >= P.len) acc -= 1e9f;
        sc[s * NHH + h] = acc;
    }
    __syncthreads();
    // softmax: wave wid handles head wid, lane = s
    {
        float v = sc[lane * NHH + wid];
        float mx = v;
        #pragma unroll
        for (int o = 32; o; o >>= 1) mx = fmaxf(mx, __shfl_xor(mx, o));
        float ex = __expf(v - mx);
        float sm = ex;
        #pragma unroll
        for (int o = 32; o; o >>= 1) sm += __shfl_xor(sm, o);
        sc[lane * NHH + wid] = ex / sm;
    }
    __syncthreads();
    if (tid < NHH * EE) {
        int h = tid / EE, e = tid - h * EE;
        float acc = 0.f;
        #pragma unroll 4
        for (int s = 0; s < SLEN; s++) acc += sc[s * NHH + h] * Xs[s * PXE + e];
        su[tid] = acc;
    }
    __syncthreads();
    if (tid < 32) {
        float acc = ldf<BF16>(bv, tid);
        int h = tid >> 2;
        for (int e = 0; e < EE; e++) acc += su[h * EE + e] * ldf<BF16>(wvv, e * 32 + tid);
        sctx[tid] = acc;
    }
    __syncthreads();
    if (tid < EE) {
        float acc = ldf<BF16>(bo, tid);
        #pragma unroll
        for (int i = 0; i < 32; i++) acc += sctx[i] * ldf<BF16>(wo, i * EE + tid);
        P.feat[176 + tid] = acc;
    }
    __syncthreads();

    // ---------------- phase 4: MLP (4-way split chains, float4 feat reads) ----------
    float z1p = 0.f;
    if (tid < H1D) {
        float a0 = ldf<BF16>(b1, tid), a1 = 0.f, a2 = 0.f, a3 = 0.f;
        #pragma unroll 2
        for (int i = 0; i < 112; i += 4) {
            float4 f4 = *(const float4*)&P.feat[i];
            a0 += f4.x * ldf<BF16>(w1, (i + 0) * H1D + tid);
            a1 += f4.y * ldf<BF16>(w1, (i + 1) * H1D + tid);
            a2 += f4.z * ldf<BF16>(w1, (i + 2) * H1D + tid);
            a3 += f4.w * ldf<BF16>(w1, (i + 3) * H1D + tid);
        }
        z1p = (a0 + a1) + (a2 + a3);
    } else if (tid >= 256 && tid < 256 + H1D) {
        int o = tid - 256;
        float a0 = 0.f, a1 = 0.f, a2 = 0.f, a3 = 0.f;
        #pragma unroll 2
        for (int i = 112; i < INDIM; i += 4) {
            float4 f4 = *(const float4*)&P.feat[i];
            a0 += f4.x * ldf<BF16>(w1, (i + 0) * H1D + o);
            a1 += f4.y * ldf<BF16>(w1, (i + 1) * H1D + o);
            a2 += f4.z * ldf<BF16>(w1, (i + 2) * H1D + o);
            a3 += f4.w * ldf<BF16>(w1, (i + 3) * H1D + o);
        }
        P.buf[640 + o] = (a0 + a1) + (a2 + a3);
    }
    __syncthreads();
    float z1 = 0.f;
    if (tid < H1D) { z1 = z1p + P.buf[640 + tid]; P.buf[tid] = z1; }
    __syncthreads();
    if (tid < 64) {
        float sm = 0.f, sq = 0.f;
        for (int j = tid; j < H1D; j += 64) { float v = P.buf[j]; sm += v; sq += v * v; }
        #pragma unroll
        for (int o = 32; o; o >>= 1) { sm += __shfl_xor(sm, o); sq += __shfl_xor(sq, o); }
        if (tid == 0) { float mu = sm / H1D; P.mu = mu; P.rstd = rsqrtf(sq / H1D - mu * mu + 1e-3f); }
    }
    __syncthreads();
    if (tid < H1D) {
        float h = fmaxf(ldf<BF16>(g1, tid) * (z1 - P.mu) * P.rstd + ldf<BF16>(be1, tid), 0.f);
        P.buf[256 + tid] = h;
    }
    __syncthreads();
    float z2p = 0.f;
    if (tid < H2D) {
        float a0 = ldf<BF16>(b2, tid), a1 = 0.f, a2 = 0.f, a3 = 0.f;
        #pragma unroll 2
        for (int i = 0; i < 100; i += 4) {
            float4 f4 = *(const float4*)&P.buf[256 + i];
            a0 += f4.x * ldf<BF16>(w2, (i + 0) * H2D + tid);
            a1 += f4.y * ldf<BF16>(w2, (i + 1) * H2D + tid);
            a2 += f4.z * ldf<BF16>(w2, (i + 2) * H2D + tid);
            a3 += f4.w * ldf<BF16>(w2, (i + 3) * H2D + tid);
        }
        z2p = (a0 + a1) + (a2 + a3);
    } else if (tid >= 256 && tid < 256 + H2D) {
        int o = tid - 256;
        float a0 = 0.f, a1 = 0.f, a2 = 0.f, a3 = 0.f;
        #pragma unroll 2
        for (int i = 100; i < H1D; i += 4) {
            float4 f4 = *(const float4*)&P.buf[256 + i];
            a0 += f4.x * ldf<BF16>(w2, (i + 0) * H2D + o);
            a1 += f4.y * ldf<BF16>(w2, (i + 1) * H2D + o);
            a2 += f4.z * ldf<BF16>(w2, (i + 2) * H2D + o);
            a3 += f4.w * ldf<BF16>(w2, (i + 3) * H2D + o);
        }
        P.buf[640 + o] = (a0 + a1) + (a2 + a3);
    }
    __syncthreads();
    float z2 = 0.f;
    if (tid < H2D) { z2 = z2p + P.buf[640 + tid]; P.buf[tid] = z2; }
    __syncthreads();
    if (tid < 64) {
        float sm = 0.f, sq = 0.f;
        for (int j = tid; j < H2D; j += 64) { float v = P.buf[j]; sm += v; sq += v * v; }
        #pragma unroll
        for (int o = 32; o; o >>= 1) { sm += __shfl_xor(sm, o); sq += __shfl_xor(sq, o); }
        if (tid == 0) { float mu = sm / H2D; P.mu = mu; P.rstd = rsqrtf(sq / H2D - mu * mu + 1e-3f); }
    }
    __syncthreads();
    if (tid < H2D) {
        float h = fmaxf(ldf<BF16>(g2, tid) * (z2 - P.mu) * P.rstd + ldf<BF16>(be2, tid), 0.f);
        P.red[tid] = h * ldf<BF16>(w3, tid);
    }
    __syncthreads();
    if (tid < 64) {
        float v = P.red[tid] + ((tid < H2D - 64) ? P.red[64 + tid] : 0.f);
        #pragma unroll
        for (int o = 32; o; o >>= 1) v += __shfl_xor(v, o);
        if (tid == 0) {
            float acc = ldf<BF16>(b3, 0) + v;
            float sig = 1.f / (1.f + __expf(-acc));
            if constexpr (BF16) ((__hip_bfloat16*)outp)[b] = __float2bfloat16(sig);
            else                ((float*)outp)[b] = sig;
        }
    }
}

__global__ __launch_bounds__(NT, 8) void sdim_fwd(
    const int* __restrict__ uid, const int* __restrict__ ut1, const int* __restrict__ ut2,
    const int* __restrict__ ut3, const int* __restrict__ ut4,
    const int* __restrict__ lb_g, const int* __restrict__ lb_s, const int* __restrict__ lb_c,
    const int* __restrict__ lt_g, const int* __restrict__ lt_s, const int* __restrict__ lt_c,
    const int* __restrict__ st_g, const int* __restrict__ st_s, const int* __restrict__ st_c,
    const void* __restrict__ tbl, const void* __restrict__ Hm,
    const void* __restrict__ wq, const void* __restrict__ bq,
    const void* __restrict__ wk, const void* __restrict__ bk,
    const void* __restrict__ wvv, const void* __restrict__ bv,
    const void* __restrict__ wo, const void* __restrict__ bo,
    const void* __restrict__ w1, const void* __restrict__ b1,
    const void* __restrict__ g1, const void* __restrict__ be1,
    const void* __restrict__ w2, const void* __restrict__ b2,
    const void* __restrict__ g2, const void* __restrict__ be2,
    const void* __restrict__ w3, const void* __restrict__ b3,
    void* __restrict__ outp)
{
    __shared__ Pool P;
    __shared__ int s_isbf;
    // in-block dtype detection: even ushort indices of bf16 data are small values
    // (exp<127); of fp32 they are random mantissa bits (P[all 128 exp<127] ~ 2^-128)
    if (threadIdx.x < 64) {
        int big = 0;
        for (int i = (threadIdx.x & 63); i < 128; i += 64) {
            unsigned short u = ((const unsigned short*)tbl)[2 * i];
            if (((u >> 7) & 0xFF) >= 127) big = 1;
        }
        unsigned long long m = __ballot(big);
        if (threadIdx.x == 0) s_isbf = (m == 0ull) ? 1 : 0;
    }
    __syncthreads();
    if (s_isbf)
        sdim_body<true >(P, uid, ut1, ut2, ut3, ut4, lb_g, lb_s, lb_c, lt_g, lt_s, lt_c,
                         st_g, st_s, st_c, tbl, Hm, wq, bq, wk, bk, wvv, bv, wo, bo,
                         w1, b1, g1, be1, w2, b2, g2, be2, w3, b3, outp);
    else
        sdim_body<false>(P, uid, ut1, ut2, ut3, ut4, lb_g, lb_s, lb_c, lt_g, lt_s, lt_c,
                         st_g, st_s, st_c, tbl, Hm, wq, bq, wk, bk, wvv, bv, wo, bo,
                         w1, b1, g1, be1, w2, b2, g2, be2, w3, b3, outp);
}

extern "C" void kernel_launch(void* const* d_in, const int* in_sizes, int n_in,
                              void* d_out, int out_size, void* d_ws, size_t ws_size,
                              hipStream_t stream) {
    const int B = in_sizes[0];   // batch = 1024
    sdim_fwd<<<B, NT, 0, stream>>>(
        (const int*)d_in[0],  (const int*)d_in[1],  (const int*)d_in[2],
        (const int*)d_in[3],  (const int*)d_in[4],
        (const int*)d_in[5],  (const int*)d_in[6],  (const int*)d_in[7],
        (const int*)d_in[8],  (const int*)d_in[9],  (const int*)d_in[10],
        (const int*)d_in[11], (const int*)d_in[12], (const int*)d_in[13],
        (const void*)d_in[14], (const void*)d_in[15],
        (const void*)d_in[16], (const void*)d_in[17],
        (const void*)d_in[18], (const void*)d_in[19],
        (const void*)d_in[20], (const void*)d_in[21],
        (const void*)d_in[22], (const void*)d_in[23],
        (const void*)d_in[24], (const void*)d_in[25],
        (const void*)d_in[26], (const void*)d_in[27],
        (const void*)d_in[28], (const void*)d_in[29],
        (const void*)d_in[30], (const void*)d_in[31],
        (const void*)d_in[32], (const void*)d_in[33],
        d_out);
}